// Round 3
// baseline (6447.791 us; speedup 1.0000x reference)
//
#include <hip/hip_runtime.h>

#define H 128
#define N_NODES 100000
#define N_EDGES 400000
#define N_INC   800000
#define BN_EPS 1e-5f

__device__ __forceinline__ float4 ld4(const float* p) { return *(const float4*)p; }
__device__ __forceinline__ void st4(float* p, float4 v) { *(float4*)p = v; }
__device__ __forceinline__ float4 bnrelu4(float4 p, float4 sc, float4 sf) {
    float4 o;
    o.x = fmaxf(fmaf(p.x, sc.x, sf.x), 0.f);
    o.y = fmaxf(fmaf(p.y, sc.y, sf.y), 0.f);
    o.z = fmaxf(fmaf(p.z, sc.z, sf.z), 0.f);
    o.w = fmaxf(fmaf(p.w, sc.w, sf.w), 0.f);
    return o;
}
__device__ __forceinline__ unsigned short f2bf(float x) {   // round-to-nearest-even
    unsigned int u = __builtin_bit_cast(unsigned int, x);
    u += 0x7fffu + ((u >> 16) & 1u);
    return (unsigned short)(u >> 16);
}
__device__ __forceinline__ float bf2f(unsigned short s) {
    unsigned int u = ((unsigned int)s) << 16;
    return __builtin_bit_cast(float, u);
}

// ---- GEMM1: gathered concat [node_rep[nidx] | edge_rep[eidx]] (800000x256) @ W1 (256x128) -> bf16 msg ----
__global__ __launch_bounds__(256) void gemm1_kernel(
    const float* __restrict__ node_rep, const float* __restrict__ edge_rep,
    const int* __restrict__ node_idx, const int* __restrict__ edge_idx,
    const float* __restrict__ W1, unsigned short* __restrict__ out)
{
    __shared__ float As[64][36];   // pad 36: rows stay float4-aligned
    __shared__ float Ws[32][128];
    __shared__ int nidx[64], eidx[64];
    const int tid = threadIdx.x;
    const int rowBase = blockIdx.x * 64;
    if (tid < 64) {
        nidx[tid] = node_idx[rowBase + tid];
        eidx[tid] = edge_idx[rowBase + tid];
    }
    __syncthreads();
    const int tx = tid & 15, ty = tid >> 4;
    float acc[4][8] = {};
    for (int kt = 0; kt < 8; ++kt) {
#pragma unroll
        for (int i = 0; i < 2; ++i) {
            int li = tid + 256 * i;
            int r = li >> 3;
            int c4 = (li & 7) * 4;
            int col = kt * 32 + c4;
            const float* src = (col < 128)
                ? node_rep + (size_t)nidx[r] * H + col
                : edge_rep + (size_t)eidx[r] * H + (col - 128);
            st4(&As[r][c4], ld4(src));
        }
#pragma unroll
        for (int i = 0; i < 4; ++i) {
            int li = tid + 256 * i;
            int r = li >> 5, c4 = (li & 31) * 4;
            st4(&Ws[r][c4], ld4(&W1[(size_t)(kt * 32 + r) * H + c4]));
        }
        __syncthreads();
#pragma unroll
        for (int k = 0; k < 32; ++k) {
            float a[4];
#pragma unroll
            for (int i = 0; i < 4; ++i) a[i] = As[ty * 4 + i][k];
            float4 w0 = ld4(&Ws[k][tx * 8]);
            float4 w1 = ld4(&Ws[k][tx * 8 + 4]);
            float w[8] = {w0.x, w0.y, w0.z, w0.w, w1.x, w1.y, w1.z, w1.w};
#pragma unroll
            for (int i = 0; i < 4; ++i)
#pragma unroll
                for (int j = 0; j < 8; ++j) acc[i][j] = fmaf(a[i], w[j], acc[i][j]);
        }
        __syncthreads();
    }
#pragma unroll
    for (int i = 0; i < 4; ++i) {
        size_t r = (size_t)(rowBase + ty * 4 + i);
        int4 p;
        p.x = f2bf(acc[i][0]) | (f2bf(acc[i][1]) << 16);
        p.y = f2bf(acc[i][2]) | (f2bf(acc[i][3]) << 16);
        p.z = f2bf(acc[i][4]) | (f2bf(acc[i][5]) << 16);
        p.w = f2bf(acc[i][6]) | (f2bf(acc[i][7]) << 16);
        *(int4*)(out + r * H + tx * 8) = p;
    }
}

// ---- Generic Mx128 @ 128x128 GEMM. mode 1: A=(1+eps)*A0+A1; mode 2: A=relu(A0*scale+shift) ----
__global__ __launch_bounds__(256) void gemm128_kernel(
    int M, int mode,
    const float* __restrict__ A0, const float* __restrict__ A1,
    const float* __restrict__ epsp, const float* __restrict__ ss,
    const float* __restrict__ W, float* __restrict__ out)
{
    __shared__ float As[64][36];
    __shared__ float Ws[32][128];
    const int tid = threadIdx.x;
    const int tx = tid & 15, ty = tid >> 4;
    const int rowBase = blockIdx.x * 64;
    const float eps = (mode == 1) ? epsp[0] : 0.f;
    float acc[4][8] = {};
    for (int kt = 0; kt < 4; ++kt) {
#pragma unroll
        for (int i = 0; i < 2; ++i) {
            int li = tid + 256 * i;
            int r = li >> 3;
            int c4 = (li & 7) * 4;
            int col = kt * 32 + c4;
            int rg = rowBase + r;
            if (rg >= M) rg = M - 1;
            float4 v;
            if (mode == 1) {
                float4 b = ld4(&A0[(size_t)rg * H + col]);
                float4 ag = ld4(&A1[(size_t)rg * H + col]);
                v.x = fmaf(eps, b.x, b.x + ag.x);
                v.y = fmaf(eps, b.y, b.y + ag.y);
                v.z = fmaf(eps, b.z, b.z + ag.z);
                v.w = fmaf(eps, b.w, b.w + ag.w);
            } else {
                float4 p = ld4(&A0[(size_t)rg * H + col]);
                float4 sc = ld4(&ss[col]);
                float4 sf = ld4(&ss[128 + col]);
                v = bnrelu4(p, sc, sf);
            }
            st4(&As[r][c4], v);
        }
#pragma unroll
        for (int i = 0; i < 4; ++i) {
            int li = tid + 256 * i;
            int r = li >> 5, c4 = (li & 31) * 4;
            st4(&Ws[r][c4], ld4(&W[(size_t)(kt * 32 + r) * H + c4]));
        }
        __syncthreads();
#pragma unroll
        for (int k = 0; k < 32; ++k) {
            float a[4];
#pragma unroll
            for (int i = 0; i < 4; ++i) a[i] = As[ty * 4 + i][k];
            float4 w0 = ld4(&Ws[k][tx * 8]);
            float4 w1 = ld4(&Ws[k][tx * 8 + 4]);
            float w[8] = {w0.x, w0.y, w0.z, w0.w, w1.x, w1.y, w1.z, w1.w};
#pragma unroll
            for (int i = 0; i < 4; ++i)
#pragma unroll
                for (int j = 0; j < 8; ++j) acc[i][j] = fmaf(a[i], w[j], acc[i][j]);
        }
        __syncthreads();
    }
#pragma unroll
    for (int i = 0; i < 4; ++i) {
        int rg = rowBase + ty * 4 + i;
        if (rg < M) {
            st4(&out[(size_t)rg * H + tx * 8],     make_float4(acc[i][0], acc[i][1], acc[i][2], acc[i][3]));
            st4(&out[(size_t)rg * H + tx * 8 + 4], make_float4(acc[i][4], acc[i][5], acc[i][6], acc[i][7]));
        }
    }
}

// ---- column sum / sumsq over Mx128 fp32 ----
__global__ __launch_bounds__(256) void stats_kernel(const float* __restrict__ X, int M,
                                                    float* __restrict__ sums)
{
    const int tid = threadIdx.x;
    const int c = tid & 127;
    const int half = tid >> 7;
    float s = 0.f, sq = 0.f;
    for (int r = blockIdx.x * 2 + half; r < M; r += gridDim.x * 2) {
        float v = X[(size_t)r * H + c];
        s += v;
        sq = fmaf(v, v, sq);
    }
    __shared__ float sh[256];
    sh[tid] = s;
    __syncthreads();
    float stot = (tid < 128) ? sh[tid] + sh[tid + 128] : 0.f;
    __syncthreads();
    sh[tid] = sq;
    __syncthreads();
    if (tid < 128) {
        float sqtot = sh[tid] + sh[tid + 128];
        atomicAdd(&sums[c], stot);
        atomicAdd(&sums[128 + c], sqtot);
    }
}

// ---- column sum / sumsq over Mx128 bf16 ----
__global__ __launch_bounds__(256) void stats_bf16_kernel(const unsigned short* __restrict__ X,
                                                         int M, float* __restrict__ sums)
{
    const int tid = threadIdx.x;
    const int c = tid & 127;
    const int half = tid >> 7;
    float s = 0.f, sq = 0.f;
    for (int r = blockIdx.x * 2 + half; r < M; r += gridDim.x * 2) {
        float v = bf2f(X[(size_t)r * H + c]);
        s += v;
        sq = fmaf(v, v, sq);
    }
    __shared__ float sh[256];
    sh[tid] = s;
    __syncthreads();
    float stot = (tid < 128) ? sh[tid] + sh[tid + 128] : 0.f;
    __syncthreads();
    sh[tid] = sq;
    __syncthreads();
    if (tid < 128) {
        float sqtot = sh[tid] + sh[tid + 128];
        atomicAdd(&sums[c], stot);
        atomicAdd(&sums[128 + c], sqtot);
    }
}

__global__ void finalize_kernel(const float* __restrict__ sums, float invM,
                                const float* __restrict__ g, const float* __restrict__ b,
                                float* __restrict__ ss)
{
    int c = threadIdx.x;  // 128 threads
    float mean = sums[c] * invM;
    float var = fmaf(-mean, mean, sums[128 + c] * invM);
    float scale = g[c] * rsqrtf(var + BN_EPS);
    ss[c] = scale;
    ss[128 + c] = fmaf(-mean, scale, b[c]);
}

// ---- scatter1: msg = bn_relu(msg_pre) in place (bf16); catm[e] += msg; lift[e] += node_rep[n] ----
__global__ __launch_bounds__(256) void scatter1_kernel(
    unsigned short* __restrict__ msg, const float* __restrict__ node_rep,
    const int* __restrict__ node_idx, const int* __restrict__ edge_idx,
    const float* __restrict__ ss, float* __restrict__ catm, float* __restrict__ lift)
{
    size_t gid = (size_t)blockIdx.x * 256 + threadIdx.x;
    size_t i = gid >> 5;
    int c = (int)(gid & 31) * 4;
    int e = edge_idx[i];
    int n = node_idx[i];
    ushort4 pb = *(const ushort4*)(msg + i * H + c);
    float4 p = make_float4(bf2f(pb.x), bf2f(pb.y), bf2f(pb.z), bf2f(pb.w));
    float4 sc = ld4(&ss[c]);
    float4 sf = ld4(&ss[128 + c]);
    float4 m = bnrelu4(p, sc, sf);
    // round to bf16 BEFORE accumulating so scatter2's (cat - msg) cancels exactly
    ushort4 mb = make_ushort4(f2bf(m.x), f2bf(m.y), f2bf(m.z), f2bf(m.w));
    *(ushort4*)(msg + i * H + c) = mb;
    float* catr = catm + (size_t)e * H + c;
    atomicAdd(catr + 0, bf2f(mb.x));
    atomicAdd(catr + 1, bf2f(mb.y));
    atomicAdd(catr + 2, bf2f(mb.z));
    atomicAdd(catr + 3, bf2f(mb.w));
    float4 nv = ld4(&node_rep[(size_t)n * H + c]);
    float* lr = lift + (size_t)e * H + c;
    atomicAdd(lr + 0, nv.x);
    atomicAdd(lr + 1, nv.y);
    atomicAdd(lr + 2, nv.z);
    atomicAdd(lr + 3, nv.w);
}

// ---- scatter2: lvl[n] += catm[e] - msg[i] ----
__global__ __launch_bounds__(256) void scatter2_kernel(
    const unsigned short* __restrict__ msg, const float* __restrict__ catm,
    const int* __restrict__ node_idx, const int* __restrict__ edge_idx,
    float* __restrict__ lvl)
{
    size_t gid = (size_t)blockIdx.x * 256 + threadIdx.x;
    size_t i = gid >> 5;
    int c = (int)(gid & 31) * 4;
    int e = edge_idx[i];
    int n = node_idx[i];
    float4 cv = ld4(&catm[(size_t)e * H + c]);
    ushort4 mb = *(const ushort4*)(msg + i * H + c);
    float* dst = lvl + (size_t)n * H + c;
    atomicAdd(dst + 0, cv.x - bf2f(mb.x));
    atomicAdd(dst + 1, cv.y - bf2f(mb.y));
    atomicAdd(dst + 2, cv.z - bf2f(mb.z));
    atomicAdd(dst + 3, cv.w - bf2f(mb.w));
}

// ---- final bn_relu apply -> fp32 out (d_out is the reference's fp32 dtype) ----
__global__ __launch_bounds__(256) void apply_kernel(const float* __restrict__ pre,
                                                    const float* __restrict__ ss,
                                                    float* __restrict__ out, int M)
{
    size_t gid = (size_t)blockIdx.x * 256 + threadIdx.x;
    size_t r = gid >> 5;
    int c = (int)(gid & 31) * 4;
    if (r >= (size_t)M) return;
    float4 p = ld4(&pre[r * H + c]);
    float4 sc = ld4(&ss[c]);
    float4 sf = ld4(&ss[128 + c]);
    st4(&out[r * H + c], bnrelu4(p, sc, sf));
}

extern "C" void kernel_launch(void* const* d_in, const int* in_sizes, int n_in,
                              void* d_out, int out_size, void* d_ws, size_t ws_size,
                              hipStream_t stream)
{
    const float* node_rep = (const float*)d_in[0];
    const float* edge_rep = (const float*)d_in[1];
    const int*   node_idx = (const int*)d_in[2];
    const int*   edge_idx = (const int*)d_in[3];
    const float* W1  = (const float*)d_in[4];
    const float* g1  = (const float*)d_in[5];
    const float* b1  = (const float*)d_in[6];
    const float* W2a = (const float*)d_in[7];
    const float* g2a = (const float*)d_in[8];
    const float* b2a = (const float*)d_in[9];
    const float* W2b = (const float*)d_in[10];
    const float* g2b = (const float*)d_in[11];
    const float* b2b = (const float*)d_in[12];
    const float* W3a = (const float*)d_in[13];
    const float* g3a = (const float*)d_in[14];
    const float* b3a = (const float*)d_in[15];
    const float* W3b = (const float*)d_in[16];
    const float* g3b = (const float*)d_in[17];
    const float* b3b = (const float*)d_in[18];
    const float* eps1 = (const float*)d_in[19];
    const float* eps2 = (const float*)d_in[20];

    float* ws  = (float*)d_ws;
    // layout (float units):
    unsigned short* msgb = (unsigned short*)ws;        // 800000*128 bf16 = 51.2M float-slots
    float* catm = ws + (size_t) 51200000;              // 400000*128 f
    float* lift = ws + (size_t)102400000;              // 400000*128 f
    float* lvl  = ws + (size_t)153600000;              // 100000*128 f
    float* stat = ws + (size_t)166400000;              // 5*256 sums + 5*256 ss
    // aliases for regions freed after scatter2:
    float* e1 = ws;                                    // msgb region (51.2M f)
    float* e2 = catm;                                  // catm region (51.2M f)
    float* n1 = lift;                                  // lift region (free after edge gemm A-load)
    float* n2 = lift + (size_t)12800000;
    float* sums0 = stat +    0; float* ss0 = stat + 1280;
    float* sums1 = stat +  256; float* ss1 = stat + 1536;
    float* sums2 = stat +  512; float* ss2 = stat + 1792;
    float* sums3 = stat +  768; float* ss3 = stat + 2048;
    float* sums4 = stat + 1024; float* ss4 = stat + 2304;

    float* out_node = (float*)d_out;
    float* out_edge = out_node + (size_t)N_NODES * H;

    // zero accumulators: catm+lift+lvl contiguous, then stat sums
    hipMemsetAsync(catm, 0, (size_t)115200000 * sizeof(float), stream);
    hipMemsetAsync(stat, 0, 1280 * sizeof(float), stream);

    // layer 1: gathered concat GEMM -> bf16 msg; BN stats
    gemm1_kernel<<<N_INC / 64, 256, 0, stream>>>(node_rep, edge_rep, node_idx, edge_idx, W1, msgb);
    stats_bf16_kernel<<<512, 256, 0, stream>>>(msgb, N_INC, sums0);
    finalize_kernel<<<1, 128, 0, stream>>>(sums0, 1.0f / N_INC, g1, b1, ss0);
    scatter1_kernel<<<N_INC / 8, 256, 0, stream>>>(msgb, node_rep, node_idx, edge_idx, ss0, catm, lift);
    scatter2_kernel<<<N_INC / 8, 256, 0, stream>>>(msgb, catm, node_idx, edge_idx, lvl);

    // edge head first (frees lift for node head): y = (1+eps2)*edge_rep + lift
    gemm128_kernel<<<N_EDGES / 64, 256, 0, stream>>>(N_EDGES, 1, edge_rep, lift, eps2, nullptr, W3a, e1);
    stats_kernel<<<512, 256, 0, stream>>>(e1, N_EDGES, sums3);
    finalize_kernel<<<1, 128, 0, stream>>>(sums3, 1.0f / N_EDGES, g3a, b3a, ss3);
    gemm128_kernel<<<N_EDGES / 64, 256, 0, stream>>>(N_EDGES, 2, e1, nullptr, nullptr, ss3, W3b, e2);
    stats_kernel<<<512, 256, 0, stream>>>(e2, N_EDGES, sums4);
    finalize_kernel<<<1, 128, 0, stream>>>(sums4, 1.0f / N_EDGES, g3b, b3b, ss4);
    apply_kernel<<<N_EDGES / 8, 256, 0, stream>>>(e2, ss4, out_edge, N_EDGES);

    // node head: x = (1+eps1)*node_rep + lvl
    gemm128_kernel<<<(N_NODES + 63) / 64, 256, 0, stream>>>(N_NODES, 1, node_rep, lvl, eps1, nullptr, W2a, n1);
    stats_kernel<<<512, 256, 0, stream>>>(n1, N_NODES, sums1);
    finalize_kernel<<<1, 128, 0, stream>>>(sums1, 1.0f / N_NODES, g2a, b2a, ss1);
    gemm128_kernel<<<(N_NODES + 63) / 64, 256, 0, stream>>>(N_NODES, 2, n1, nullptr, nullptr, ss1, W2b, n2);
    stats_kernel<<<512, 256, 0, stream>>>(n2, N_NODES, sums2);
    finalize_kernel<<<1, 128, 0, stream>>>(sums2, 1.0f / N_NODES, g2b, b2b, ss2);
    apply_kernel<<<N_NODES / 8, 256, 0, stream>>>(n2, ss2, out_node, N_NODES);
}